// Round 5
// baseline (1032.731 us; speedup 1.0000x reference)
//
#include <hip/hip_runtime.h>

#define N_ZONE 100000
#define E_ZONE 2000000
#define N_OUT  50000
#define E_OUT  1000000
#define N_GND  50000
#define E_GND  1000000
#define HID    64
#define N_TOT   (N_ZONE + N_OUT + N_GND)     // 200000
#define E_TOTAL (E_ZONE + E_OUT + E_GND)     // 4000000

// ---- binning geometry ----
#define RANGE   2048
#define RSHIFT  11
#define NBZ     49
#define NBO     25
#define NBG     25
#define NBUCKET (NBZ + NBO + NBG)            // 99
#define SLICES  8
#define NTASK   (NBUCKET * SLICES)           // 792
#define OUT_PAD_BASE (NBZ * RANGE)           // 100352
#define GND_PAD_BASE ((NBZ + NBO) * RANGE)   // 151552
#define PAD_TOT      (NBUCKET * RANGE)       // 202752

#define GRID  768            // 3 blocks/CU; residency cap is 4/CU (VGPR<=128, LDS 25KB) -> no deadlock
#define BLK   256
#define CHUNK 2048
#define NCHUNK ((E_TOTAL + CHUNK - 1) / CHUNK)   // 1954

// ---- ws layout (32-bit words). NO region overlays (single-writer-then-reader only). ----
#define WFLAG 0
#define WBARC 16
#define WCNT  64                              // CNT[99]
#define WBASE 192                             // BASE[99]
#define WCUR  320                             // CUR[99]
#define WREC  512                             // uint2 rec[4M] = 8M words
#define WPDEG (WREC + 2 * E_TOTAL)            // 792*2048
#define WPSZ  (WPDEG + NTASK * RANGE)
#define WPSO  (WPSZ + NBZ * SLICES * RANGE * 2)
#define WPSG  (WPSO + NBO * SLICES * RANGE * 3)
#define WDINV (WPSG + NBG * SLICES * RANGE)
#define WY    (WDINV + PAD_TOT)
#define WYZ   WY
#define WYO   (WY + 2 * N_ZONE)
#define WYG   (WYO + 4 * N_OUT)
#define WU    (WY + 450000)
#define WUZ   WU
#define WUO   (WU + 2 * N_ZONE)
#define WUG   (WUO + 4 * N_OUT)
#define WTOT  (WU + 450000)                   // 13,969,312 words = 55.88 MB
#define FAST_WS_BYTES ((size_t)WTOT * 4)

#define MAGIC 0x5EED5EEDu

__device__ __forceinline__ void gbar(unsigned* ctr, unsigned target) {
    __syncthreads();
    if (threadIdx.x == 0) {
        __threadfence();   // order + L2 writeback of this XCD's prior writes
        __hip_atomic_fetch_add(ctr, 1u, __ATOMIC_ACQ_REL, __HIP_MEMORY_SCOPE_AGENT);
        while (__hip_atomic_load(ctr, __ATOMIC_ACQUIRE, __HIP_MEMORY_SCOPE_AGENT) < target)
            __builtin_amdgcn_s_sleep(64);
        __threadfence();   // acquire: invalidate stale L1/L2 lines before plain reads
    }
    __syncthreads();
}

__global__ __launch_bounds__(BLK, 4)
void mega(const int* __restrict__ eiz, const float* __restrict__ wz,
          const int* __restrict__ eio, const float* __restrict__ wo,
          const int* __restrict__ eig, const float* __restrict__ wg,
          const float* __restrict__ xz, const float* __restrict__ xo,
          const float* __restrict__ xg,
          const float* __restrict__ Wz, const float* __restrict__ bz,
          const float* __restrict__ Wo, const float* __restrict__ bo,
          const float* __restrict__ Wg, const float* __restrict__ bg,
          float* __restrict__ out, float* __restrict__ ws) {
    __shared__ __align__(16) float smem[RANGE * 3];      // 24 KB, reused per phase
    __shared__ unsigned hist[NBUCKET], sbase[NBUCKET], gbase[NBUCKET];

    unsigned* uws = (unsigned*)ws;
    unsigned* ctr = uws + WBARC;
    const int tid = threadIdx.x;
    const int bid = blockIdx.x;
    const int nb  = gridDim.x;
    const int gstride = nb * BLK;
    uint2* rec = (uint2*)(ws + WREC);

    // ---- init gate (ws is poisoned 0xAA each call) ----
    if (bid == 0) {
        if (tid < NBUCKET)
            __hip_atomic_store(&uws[WCNT + tid], 0u, __ATOMIC_RELAXED, __HIP_MEMORY_SCOPE_AGENT);
        __syncthreads();
        if (tid == 0) {
            __hip_atomic_store(ctr, 0u, __ATOMIC_RELAXED, __HIP_MEMORY_SCOPE_AGENT);
            __threadfence();
            __hip_atomic_store(&uws[WFLAG], MAGIC, __ATOMIC_RELEASE, __HIP_MEMORY_SCOPE_AGENT);
        }
    }
    if (tid == 0) {
        while (__hip_atomic_load(&uws[WFLAG], __ATOMIC_ACQUIRE, __HIP_MEMORY_SCOPE_AGENT) != MAGIC)
            __builtin_amdgcn_s_sleep(32);
        __threadfence();
    }
    __syncthreads();

    // ---- P1: bucket histogram of col destinations -> CNT ----
    for (int b = tid; b < NBUCKET; b += BLK) hist[b] = 0;
    __syncthreads();
    for (int t = bid * BLK + tid; t < E_TOTAL; t += gstride) {
        int b;
        if (t < E_ZONE) b = eiz[E_ZONE + t] >> RSHIFT;
        else if (t < E_ZONE + E_OUT) b = NBZ + (eio[E_OUT + (t - E_ZONE)] >> RSHIFT);
        else b = NBZ + NBO + (eig[E_GND + (t - E_ZONE - E_OUT)] >> RSHIFT);
        atomicAdd(&hist[b], 1u);
    }
    __syncthreads();
    for (int b = tid; b < NBUCKET; b += BLK)
        if (hist[b]) atomicAdd(&uws[WCNT + b], hist[b]);
    gbar(ctr, 1u * nb);

    // ---- P2: scan CNT -> BASE, CUR (block 0) ----
    if (bid == 0) {
        if (tid < NBUCKET)
            hist[tid] = __hip_atomic_load(&uws[WCNT + tid], __ATOMIC_RELAXED, __HIP_MEMORY_SCOPE_AGENT);
        __syncthreads();
        if (tid == 0) {
            unsigned acc = 0;
            for (int b = 0; b < NBUCKET; b++) { unsigned c = hist[b]; hist[b] = acc; acc += c; }
        }
        __syncthreads();
        if (tid < NBUCKET) {
            __hip_atomic_store(&uws[WBASE + tid], hist[tid], __ATOMIC_RELAXED, __HIP_MEMORY_SCOPE_AGENT);
            __hip_atomic_store(&uws[WCUR + tid],  hist[tid], __ATOMIC_RELAXED, __HIP_MEMORY_SCOPE_AGENT);
        }
    }
    gbar(ctr, 2u * nb);

    // ---- P3: bin edges -> bucket-contiguous rec ----
    {
        unsigned* la = (unsigned*)smem;
        float*    lw = smem + CHUNK;
        for (int c = bid; c < NCHUNK; c += nb) {
            for (int b = tid; b < NBUCKET; b += BLK) hist[b] = 0;
            __syncthreads();
            unsigned mya[CHUNK / BLK], mybk[CHUNK / BLK], myr[CHUNK / BLK];
            float myw[CHUNK / BLK];
            int t0 = c * CHUNK;
#pragma unroll
            for (int i = 0; i < CHUNK / BLK; i++) {
                int t = t0 + i * BLK + tid;
                unsigned b = 0xFFFFFFFFu;
                if (t < E_TOTAL) {
                    int row, col; float w;
                    if (t < E_ZONE) { row = eiz[t]; col = eiz[E_ZONE + t]; w = wz[t]; b = col >> RSHIFT; }
                    else if (t < E_ZONE + E_OUT) { int e = t - E_ZONE; row = eio[e]; col = eio[E_OUT + e]; w = wo[e]; b = NBZ + (col >> RSHIFT); }
                    else { int e = t - E_ZONE - E_OUT; row = eig[e]; col = eig[E_GND + e]; w = wg[e]; b = NBZ + NBO + (col >> RSHIFT); }
                    mya[i] = ((unsigned)(col & (RANGE - 1)) << 17) | (unsigned)row;
                    myw[i] = w;
                    myr[i] = atomicAdd(&hist[b], 1u);
                }
                mybk[i] = b;
            }
            __syncthreads();
            if (tid == 0) {
                unsigned acc = 0;
                for (int b = 0; b < NBUCKET; b++) { sbase[b] = acc; acc += hist[b]; }
            }
            __syncthreads();
            for (int b = tid; b < NBUCKET; b += BLK)
                gbase[b] = hist[b] ? atomicAdd(&uws[WCUR + b], hist[b]) : 0u;
            __syncthreads();
#pragma unroll
            for (int i = 0; i < CHUNK / BLK; i++) {
                if (mybk[i] < NBUCKET) {
                    unsigned p = sbase[mybk[i]] + myr[i];
                    la[p] = mya[i]; lw[p] = myw[i];
                }
            }
            __syncthreads();
            int wid = tid >> 6, lane = tid & 63;
            for (int b = wid; b < NBUCKET; b += 4) {
                unsigned cc = hist[b], gb = gbase[b], sb = sbase[b];
                for (unsigned j = lane; j < cc; j += 64)
                    rec[gb + j] = make_uint2(la[sb + j], __float_as_uint(lw[sb + j]));
            }
            __syncthreads();
        }
    }
    gbar(ctr, 3u * nb);

    // ---- P4: deg partials per (bucket, slice) ----
    for (int task = bid; task < NTASK; task += nb) {
        int r = task / SLICES, sl = task % SLICES;
        for (int i = tid; i < RANGE; i += BLK) smem[i] = 0.0f;
        __syncthreads();
        unsigned c = uws[WCNT + r], b0 = uws[WBASE + r];
        unsigned per = (c + SLICES - 1) / SLICES;
        unsigned s0 = sl * per, s1 = s0 + per; if (s1 > c) s1 = c;
        for (unsigned j = s0 + tid; j < s1; j += BLK) {
            uint2 q = rec[b0 + j];
            atomicAdd(&smem[q.x >> 17], __uint_as_float(q.y));
        }
        __syncthreads();
        float* o = ws + WPDEG + (size_t)task * RANGE;
        for (int i = tid * 4; i < RANGE; i += BLK * 4)
            *(float4*)&o[i] = *(float4*)&smem[i];
        __syncthreads();
    }
    gbar(ctr, 4u * nb);

    // ---- P5: reduce deg -> dinv; y = dinv * x ----
    for (int p = bid * BLK + tid; p < PAD_TOT; p += gstride) {
        int r = p >> RSHIFT, i = p & (RANGE - 1);
        float d = 1.0f;
#pragma unroll
        for (int sl = 0; sl < SLICES; sl++)
            d += ws[WPDEG + (size_t)(r * SLICES + sl) * RANGE + i];
        float di = rsqrtf(d);
        ws[WDINV + p] = di;
        if (p < OUT_PAD_BASE) {
            if (p < N_ZONE) {
                ws[WYZ + 2 * p]     = di * xz[2 * p];
                ws[WYZ + 2 * p + 1] = di * xz[2 * p + 1];
            }
        } else if (p < GND_PAD_BASE) {
            int idx = p - OUT_PAD_BASE;
            if (idx < N_OUT) {
                ws[WYO + 4 * idx]     = di * xo[3 * idx];
                ws[WYO + 4 * idx + 1] = di * xo[3 * idx + 1];
                ws[WYO + 4 * idx + 2] = di * xo[3 * idx + 2];
                ws[WYO + 4 * idx + 3] = 0.0f;
            }
        } else {
            int idx = p - GND_PAD_BASE;
            if (idx < N_GND) ws[WYG + idx] = di * xg[idx];
        }
    }
    gbar(ctr, 5u * nb);

    // ---- P6: s partials per (bucket, slice), LDS accumulate ----
    for (int task = bid; task < NTASK; task += nb) {
        int r = task / SLICES, sl = task % SLICES;
        int ch, rg; size_t yoff, psoff;
        if (r < NBZ)            { ch = 2; rg = r;             yoff = WYZ; psoff = WPSZ; }
        else if (r < NBZ + NBO) { ch = 3; rg = r - NBZ;       yoff = WYO; psoff = WPSO; }
        else                    { ch = 1; rg = r - NBZ - NBO; yoff = WYG; psoff = WPSG; }
        int tot = RANGE * ch;
        for (int i = tid; i < tot; i += BLK) smem[i] = 0.0f;
        __syncthreads();
        unsigned c = uws[WCNT + r], b0 = uws[WBASE + r];
        unsigned per = (c + SLICES - 1) / SLICES;
        unsigned s0 = sl * per, s1 = s0 + per; if (s1 > c) s1 = c;
        if (ch == 2) {
            const float2* y = (const float2*)(ws + yoff);
            for (unsigned j = s0 + tid; j < s1; j += BLK) {
                uint2 q = rec[b0 + j];
                unsigned colr = q.x >> 17, row = q.x & 0x1FFFFu;
                float w = __uint_as_float(q.y);
                float2 yv = y[row];
                atomicAdd(&smem[colr * 2],     w * yv.x);
                atomicAdd(&smem[colr * 2 + 1], w * yv.y);
            }
        } else if (ch == 3) {
            const float4* y = (const float4*)(ws + yoff);
            for (unsigned j = s0 + tid; j < s1; j += BLK) {
                uint2 q = rec[b0 + j];
                unsigned colr = q.x >> 17, row = q.x & 0x1FFFFu;
                float w = __uint_as_float(q.y);
                float4 yv = y[row];
                atomicAdd(&smem[colr * 3],     w * yv.x);
                atomicAdd(&smem[colr * 3 + 1], w * yv.y);
                atomicAdd(&smem[colr * 3 + 2], w * yv.z);
            }
        } else {
            const float* y = ws + yoff;
            for (unsigned j = s0 + tid; j < s1; j += BLK) {
                uint2 q = rec[b0 + j];
                atomicAdd(&smem[q.x >> 17], __uint_as_float(q.y) * y[q.x & 0x1FFFFu]);
            }
        }
        __syncthreads();
        float* o = ws + psoff + (size_t)(rg * SLICES + sl) * tot;
        for (int i = tid * 4; i < tot; i += BLK * 4)
            *(float4*)&o[i] = *(float4*)&smem[i];
        __syncthreads();
    }
    gbar(ctr, 6u * nb);

    // ---- P7: u = dinv * (y + sum partials) ----
    for (int p = bid * BLK + tid; p < PAD_TOT; p += gstride) {
        int r = p >> RSHIFT, i = p & (RANGE - 1);
        float di = ws[WDINV + p];
        if (p < OUT_PAD_BASE) {
            if (p >= N_ZONE) continue;
            float s0 = ws[WYZ + 2 * p], s1 = ws[WYZ + 2 * p + 1];
#pragma unroll
            for (int sl = 0; sl < SLICES; sl++) {
                const float* ps = ws + WPSZ + (size_t)(r * SLICES + sl) * RANGE * 2;
                s0 += ps[2 * i]; s1 += ps[2 * i + 1];
            }
            ws[WUZ + 2 * p] = di * s0; ws[WUZ + 2 * p + 1] = di * s1;
        } else if (p < GND_PAD_BASE) {
            int idx = p - OUT_PAD_BASE;
            if (idx >= N_OUT) continue;
            int rg = r - NBZ;
            float s0 = ws[WYO + 4 * idx], s1 = ws[WYO + 4 * idx + 1], s2 = ws[WYO + 4 * idx + 2];
#pragma unroll
            for (int sl = 0; sl < SLICES; sl++) {
                const float* ps = ws + WPSO + (size_t)(rg * SLICES + sl) * RANGE * 3;
                s0 += ps[3 * i]; s1 += ps[3 * i + 1]; s2 += ps[3 * i + 2];
            }
            ws[WUO + 4 * idx] = di * s0; ws[WUO + 4 * idx + 1] = di * s1; ws[WUO + 4 * idx + 2] = di * s2;
        } else {
            int idx = p - GND_PAD_BASE;
            if (idx >= N_GND) continue;
            int rg = r - NBZ - NBO;
            float s0 = ws[WYG + idx];
#pragma unroll
            for (int sl = 0; sl < SLICES; sl++)
                s0 += ws[WPSG + (size_t)(rg * SLICES + sl) * RANGE + i];
            ws[WUG + idx] = di * s0;
        }
    }
    gbar(ctr, 7u * nb);

    // ---- P8: out = relu(u @ W + b), float4 stores ----
    {
        const int TZ4 = N_ZONE * 16, TO4 = TZ4 + N_OUT * 16, TG4 = TO4 + N_GND * 16;
        for (int t = bid * BLK + tid; t < TG4; t += gstride) {
            if (t < TZ4) {
                int i = t >> 4, jb = (t & 15) << 2;
                float u0 = ws[WUZ + 2 * i], u1 = ws[WUZ + 2 * i + 1];
                float4 w0 = *(const float4*)(Wz + jb);
                float4 w1 = *(const float4*)(Wz + HID + jb);
                float4 bv = *(const float4*)(bz + jb);
                float4 o;
                o.x = fmaxf(bv.x + u0 * w0.x + u1 * w1.x, 0.0f);
                o.y = fmaxf(bv.y + u0 * w0.y + u1 * w1.y, 0.0f);
                o.z = fmaxf(bv.z + u0 * w0.z + u1 * w1.z, 0.0f);
                o.w = fmaxf(bv.w + u0 * w0.w + u1 * w1.w, 0.0f);
                *(float4*)(out + i * HID + jb) = o;
            } else if (t < TO4) {
                int q = t - TZ4;
                int i = q >> 4, jb = (q & 15) << 2;
                const float* u = ws + WUO + 4 * i;
                float u0 = u[0], u1 = u[1], u2 = u[2];
                float4 w0 = *(const float4*)(Wo + jb);
                float4 w1 = *(const float4*)(Wo + HID + jb);
                float4 w2 = *(const float4*)(Wo + 2 * HID + jb);
                float4 bv = *(const float4*)(bo + jb);
                float4 o;
                o.x = fmaxf(bv.x + u0 * w0.x + u1 * w1.x + u2 * w2.x, 0.0f);
                o.y = fmaxf(bv.y + u0 * w0.y + u1 * w1.y + u2 * w2.y, 0.0f);
                o.z = fmaxf(bv.z + u0 * w0.z + u1 * w1.z + u2 * w2.z, 0.0f);
                o.w = fmaxf(bv.w + u0 * w0.w + u1 * w1.w + u2 * w2.w, 0.0f);
                *(float4*)(out + N_ZONE * HID + i * HID + jb) = o;
            } else {
                int q = t - TO4;
                int i = q >> 4, jb = (q & 15) << 2;
                float u0 = ws[WUG + i];
                float4 w0 = *(const float4*)(Wg + jb);
                float4 bv = *(const float4*)(bg + jb);
                float4 o;
                o.x = fmaxf(bv.x + u0 * w0.x, 0.0f);
                o.y = fmaxf(bv.y + u0 * w0.y, 0.0f);
                o.z = fmaxf(bv.z + u0 * w0.z, 0.0f);
                o.w = fmaxf(bv.w + u0 * w0.w, 0.0f);
                *(float4*)(out + (N_ZONE + N_OUT) * HID + i * HID + jb) = o;
            }
        }
    }
}

// ---------------- fallback path (proven R1 kernels, 2.4 MB ws) ----------------
#define F_DEG_Z   0
#define F_DEG_O   (N_ZONE)
#define F_DEG_G   (N_ZONE + N_OUT)
#define F_DEG_TOT N_TOT
#define F_S_Z     F_DEG_TOT
#define F_S_O     (F_S_Z + N_ZONE * 2)
#define F_S_G     (F_S_O + N_OUT * 3)
#define F_TOT     (F_S_G + N_GND * 1)

__global__ void f_init(float* __restrict__ ws) {
    int i = blockIdx.x * blockDim.x + threadIdx.x;
    if (i < F_TOT) ws[i] = (i < F_DEG_TOT) ? 1.0f : 0.0f;
}
__global__ void f_deg(const int* __restrict__ eiz, const float* __restrict__ wz,
                      const int* __restrict__ eio, const float* __restrict__ wo,
                      const int* __restrict__ eig, const float* __restrict__ wg,
                      float* __restrict__ ws) {
    int t = blockIdx.x * blockDim.x + threadIdx.x;
    if (t < E_ZONE) atomicAdd(ws + F_DEG_Z + eiz[E_ZONE + t], wz[t]);
    else if (t < E_ZONE + E_OUT) { int e = t - E_ZONE; atomicAdd(ws + F_DEG_O + eio[E_OUT + e], wo[e]); }
    else if (t < E_ZONE + E_OUT + E_GND) { int e = t - E_ZONE - E_OUT; atomicAdd(ws + F_DEG_G + eig[E_GND + e], wg[e]); }
}
__global__ void f_dinv(float* __restrict__ ws) {
    int i = blockIdx.x * blockDim.x + threadIdx.x;
    if (i < F_DEG_TOT) ws[i] = 1.0f / sqrtf(ws[i]);
}
__global__ void f_scatter(const int* __restrict__ eiz, const float* __restrict__ wz, const float* __restrict__ xz,
                          const int* __restrict__ eio, const float* __restrict__ wo, const float* __restrict__ xo,
                          const int* __restrict__ eig, const float* __restrict__ wg, const float* __restrict__ xg,
                          float* __restrict__ ws) {
    int t = blockIdx.x * blockDim.x + threadIdx.x;
    if (t < E_ZONE) {
        int row = eiz[t], col = eiz[E_ZONE + t];
        float n = ws[F_DEG_Z + row] * wz[t] * ws[F_DEG_Z + col];
        atomicAdd(ws + F_S_Z + col * 2 + 0, n * xz[row * 2 + 0]);
        atomicAdd(ws + F_S_Z + col * 2 + 1, n * xz[row * 2 + 1]);
    } else if (t < E_ZONE + E_OUT) {
        int e = t - E_ZONE;
        int row = eio[e], col = eio[E_OUT + e];
        float n = ws[F_DEG_O + row] * wo[e] * ws[F_DEG_O + col];
        atomicAdd(ws + F_S_O + col * 3 + 0, n * xo[row * 3 + 0]);
        atomicAdd(ws + F_S_O + col * 3 + 1, n * xo[row * 3 + 1]);
        atomicAdd(ws + F_S_O + col * 3 + 2, n * xo[row * 3 + 2]);
    } else if (t < E_ZONE + E_OUT + E_GND) {
        int e = t - E_ZONE - E_OUT;
        int row = eig[e], col = eig[E_GND + e];
        float n = ws[F_DEG_G + row] * wg[e] * ws[F_DEG_G + col];
        atomicAdd(ws + F_S_G + col, n * xg[row]);
    }
}
__global__ void f_final(const float* __restrict__ ws,
                        const float* __restrict__ xz, const float* __restrict__ Wz, const float* __restrict__ bz,
                        const float* __restrict__ xo, const float* __restrict__ Wo, const float* __restrict__ bo,
                        const float* __restrict__ xg, const float* __restrict__ Wg, const float* __restrict__ bg,
                        float* __restrict__ out) {
    int t = blockIdx.x * blockDim.x + threadIdx.x;
    const int TZ = N_ZONE * HID, TO = TZ + N_OUT * HID, TG = TO + N_GND * HID;
    if (t < TZ) {
        int i = t >> 6, j = t & 63;
        float di = ws[F_DEG_Z + i], d2 = di * di;
        float t0 = ws[F_S_Z + i * 2 + 0] + d2 * xz[i * 2 + 0];
        float t1 = ws[F_S_Z + i * 2 + 1] + d2 * xz[i * 2 + 1];
        out[t] = fmaxf(bz[j] + t0 * Wz[j] + t1 * Wz[HID + j], 0.0f);
    } else if (t < TO) {
        int u = t - TZ;
        int i = u >> 6, j = u & 63;
        float di = ws[F_DEG_O + i], d2 = di * di;
        float t0 = ws[F_S_O + i * 3 + 0] + d2 * xo[i * 3 + 0];
        float t1 = ws[F_S_O + i * 3 + 1] + d2 * xo[i * 3 + 1];
        float t2 = ws[F_S_O + i * 3 + 2] + d2 * xo[i * 3 + 2];
        out[t] = fmaxf(bo[j] + t0 * Wo[j] + t1 * Wo[HID + j] + t2 * Wo[2 * HID + j], 0.0f);
    } else if (t < TG) {
        int u = t - TO;
        int i = u >> 6, j = u & 63;
        float di = ws[F_DEG_G + i], d2 = di * di;
        float t0 = ws[F_S_G + i] + d2 * xg[i];
        out[t] = fmaxf(bg[j] + t0 * Wg[j], 0.0f);
    }
}

extern "C" void kernel_launch(void* const* d_in, const int* in_sizes, int n_in,
                              void* d_out, int out_size, void* d_ws, size_t ws_size,
                              hipStream_t stream) {
    const float* xz = (const float*)d_in[0];
    const float* xo = (const float*)d_in[1];
    const float* xg = (const float*)d_in[2];
    const int*  eiz = (const int*)d_in[3];
    const int*  eio = (const int*)d_in[4];
    const int*  eig = (const int*)d_in[5];
    const float* Wz = (const float*)d_in[6];
    const float* Wo = (const float*)d_in[7];
    const float* Wg = (const float*)d_in[8];
    const float* bz = (const float*)d_in[9];
    const float* bo = (const float*)d_in[10];
    const float* bg = (const float*)d_in[11];
    const float* wz = (const float*)d_in[12];
    const float* wo = (const float*)d_in[13];
    const float* wg = (const float*)d_in[14];
    float* out = (float*)d_out;
    float* ws  = (float*)d_ws;

    const int B = 256;

    if (ws_size >= FAST_WS_BYTES) {
        mega<<<GRID, BLK, 0, stream>>>(eiz, wz, eio, wo, eig, wg,
                                       xz, xo, xg, Wz, bz, Wo, bo, Wg, bg, out, ws);
    } else {
        const int E_TOT = E_TOTAL, OUT_TOT = N_TOT * HID;
        f_init<<<(F_TOT + B - 1) / B, B, 0, stream>>>(ws);
        f_deg<<<(E_TOT + B - 1) / B, B, 0, stream>>>(eiz, wz, eio, wo, eig, wg, ws);
        f_dinv<<<(F_DEG_TOT + B - 1) / B, B, 0, stream>>>(ws);
        f_scatter<<<(E_TOT + B - 1) / B, B, 0, stream>>>(eiz, wz, xz, eio, wo, xo, eig, wg, xg, ws);
        f_final<<<(OUT_TOT + B - 1) / B, B, 0, stream>>>(ws, xz, Wz, bz, xo, Wo, bo, xg, Wg, bg, out);
    }
}

// Round 6
// 248.343 us; speedup vs baseline: 4.1585x; 4.1585x over previous
//
#include <hip/hip_runtime.h>

#define N_ZONE 100000
#define E_ZONE 2000000
#define N_OUT  50000
#define E_OUT  1000000
#define N_GND  50000
#define E_GND  1000000
#define HID    64
#define N_TOT   (N_ZONE + N_OUT + N_GND)     // 200000
#define E_TOTAL (E_ZONE + E_OUT + E_GND)     // 4000000

// ---- binning geometry ----
#define RANGE   2048
#define RSHIFT  11
#define NBZ     49
#define NBO     25
#define NBG     25
#define NBUCKET (NBZ + NBO + NBG)            // 99
#define SL      16                           // slices per bucket
#define CAP     49152                        // fixed bucket capacity (mean ~40.6k, sigma ~200)
#define OUT_PAD_BASE (NBZ * RANGE)           // 100352
#define GND_PAD_BASE ((NBZ + NBO) * RANGE)   // 151552
#define PAD_TOT      (NBUCKET * RANGE)       // 202752

#define CHUNK  4096
#define NCHUNK ((E_TOTAL + CHUNK - 1) / CHUNK)   // 977

// ---- ws layout (32-bit words), no overlays ----
#define WCUR  0                               // u32 CUR[128] (bucket fill counts)
#define WREC  128                             // uint2 rec[99*CAP]
#define WPDEG (WREC + 2 * NBUCKET * CAP)      // 99*16*2048
#define WPSZ  (WPDEG + NBUCKET * SL * RANGE)
#define WPSO  (WPSZ + NBZ * SL * RANGE * 2)
#define WPSG  (WPSO + NBO * SL * RANGE * 3)
#define WDINV (WPSG + NBG * SL * RANGE)
#define WYZ   (WDINV + PAD_TOT)
#define WYO   (WYZ + 2 * N_ZONE)
#define WYG   (WYO + 4 * N_OUT)
#define WUZ   (WYG + N_GND)
#define WUO   (WUZ + 2 * N_ZONE)
#define WUG   (WUO + 4 * N_OUT)
#define WTOT  (WUG + N_GND)                   // 20,567,072 words = 82.3 MB
#define FAST_WS_BYTES ((size_t)WTOT * 4)

// K1: single-pass bin: stage chunk in LDS ordered by bucket, bump-allocate into
// fixed-CAP bucket regions, dense binary-search copy-out.
__global__ void k_bin(const int* __restrict__ eiz, const float* __restrict__ wz,
                      const int* __restrict__ eio, const float* __restrict__ wo,
                      const int* __restrict__ eig, const float* __restrict__ wg,
                      unsigned* __restrict__ cur, uint2* __restrict__ rec) {
    __shared__ unsigned la[CHUNK];
    __shared__ float    lw[CHUNK];
    __shared__ unsigned hist[NBUCKET];
    __shared__ unsigned sbase[NBUCKET + 1];
    __shared__ unsigned gbase[NBUCKET];
    int tid = threadIdx.x;
    for (int b = tid; b < NBUCKET; b += 256) hist[b] = 0;
    __syncthreads();
    int t0 = blockIdx.x * CHUNK;
    unsigned mya[CHUNK / 256], mybk[CHUNK / 256], myr[CHUNK / 256];
    float myw[CHUNK / 256];
#pragma unroll
    for (int i = 0; i < CHUNK / 256; i++) {
        int t = t0 + i * 256 + tid;
        unsigned b = 0xFFFFFFFFu;
        if (t < E_TOTAL) {
            int row, col; float w;
            if (t < E_ZONE) { row = eiz[t]; col = eiz[E_ZONE + t]; w = wz[t]; b = col >> RSHIFT; }
            else if (t < E_ZONE + E_OUT) { int e = t - E_ZONE; row = eio[e]; col = eio[E_OUT + e]; w = wo[e]; b = NBZ + (col >> RSHIFT); }
            else { int e = t - E_ZONE - E_OUT; row = eig[e]; col = eig[E_GND + e]; w = wg[e]; b = NBZ + NBO + (col >> RSHIFT); }
            mya[i] = ((unsigned)(col & (RANGE - 1)) << 17) | (unsigned)row;
            myw[i] = w;
            myr[i] = atomicAdd(&hist[b], 1u);
        }
        mybk[i] = b;
    }
    __syncthreads();
    if (tid == 0) {
        unsigned acc = 0;
        for (int b = 0; b < NBUCKET; b++) { sbase[b] = acc; acc += hist[b]; }
        sbase[NBUCKET] = acc;
    }
    __syncthreads();
    if (tid < NBUCKET)
        gbase[tid] = hist[tid] ? atomicAdd(&cur[tid], hist[tid]) : 0u;
#pragma unroll
    for (int i = 0; i < CHUNK / 256; i++) {
        if (mybk[i] < NBUCKET) {
            unsigned p = sbase[mybk[i]] + myr[i];
            la[p] = mya[i]; lw[p] = myw[i];
        }
    }
    __syncthreads();
    unsigned total = sbase[NBUCKET];
    for (unsigned p = tid; p < total; p += 256) {
        // binary search: largest b with sbase[b] <= p
        int lo = 0, hi = NBUCKET;
        while (hi - lo > 1) { int mid = (lo + hi) >> 1; if (sbase[mid] <= p) lo = mid; else hi = mid; }
        unsigned idx = (unsigned)lo * CAP + gbase[lo] + (p - sbase[lo]);
        rec[idx] = make_uint2(la[p], __float_as_uint(lw[p]));
    }
}

// K2: per (bucket, slice): LDS-accumulate deg, write dense partial
__global__ void k_degp(const uint2* __restrict__ rec, const unsigned* __restrict__ cur,
                       float* __restrict__ pdeg) {
    __shared__ float deg[RANGE];
    int r = blockIdx.x / SL, sl = blockIdx.x % SL, tid = threadIdx.x;
    for (int i = tid; i < RANGE; i += 256) deg[i] = 0.0f;
    __syncthreads();
    unsigned c = cur[r];
    size_t b0 = (size_t)r * CAP;
    unsigned per = (c + SL - 1) / SL;
    unsigned s0 = sl * per, s1 = s0 + per; if (s1 > c) s1 = c;
    for (unsigned j = s0 + tid; j < s1; j += 256) {
        uint2 q = rec[b0 + j];
        atomicAdd(&deg[q.x >> 17], __uint_as_float(q.y));
    }
    __syncthreads();
    float* o = pdeg + (size_t)blockIdx.x * RANGE;
    for (int i = tid * 4; i < RANGE; i += 1024)
        *(float4*)&o[i] = *(float4*)&deg[i];
}

// K3: reduce deg partials -> dinv; y = dinv * x
__global__ void k_dinvy(const float* __restrict__ xz, const float* __restrict__ xo,
                        const float* __restrict__ xg, float* __restrict__ ws) {
    int p = blockIdx.x * blockDim.x + threadIdx.x;
    if (p >= PAD_TOT) return;
    int r = p >> RSHIFT, i = p & (RANGE - 1);
    float d = 1.0f;
#pragma unroll
    for (int sl = 0; sl < SL; sl++)
        d += ws[WPDEG + (size_t)(r * SL + sl) * RANGE + i];
    float di = rsqrtf(d);
    ws[WDINV + p] = di;
    if (p < OUT_PAD_BASE) {
        if (p < N_ZONE) {
            ws[WYZ + 2 * p]     = di * xz[2 * p];
            ws[WYZ + 2 * p + 1] = di * xz[2 * p + 1];
        }
    } else if (p < GND_PAD_BASE) {
        int idx = p - OUT_PAD_BASE;
        if (idx < N_OUT) {
            ws[WYO + 4 * idx]     = di * xo[3 * idx];
            ws[WYO + 4 * idx + 1] = di * xo[3 * idx + 1];
            ws[WYO + 4 * idx + 2] = di * xo[3 * idx + 2];
            ws[WYO + 4 * idx + 3] = 0.0f;
        }
    } else {
        int idx = p - GND_PAD_BASE;
        if (idx < N_GND) ws[WYG + idx] = di * xg[idx];
    }
}

// K4: per (bucket, slice): LDS-accumulate s[col][ch] += w*y[row][ch], unified 3 graphs
__global__ void k_sp(float* __restrict__ ws) {
    __shared__ __align__(16) float s[RANGE * 3];     // 24 KB
    int r = blockIdx.x / SL, sl = blockIdx.x % SL, tid = threadIdx.x;
    const unsigned* cur = (const unsigned*)(ws + WCUR);
    const uint2* rec = (const uint2*)(ws + WREC);
    int ch, rg; size_t yoff, psoff;
    if (r < NBZ)            { ch = 2; rg = r;             yoff = WYZ; psoff = WPSZ; }
    else if (r < NBZ + NBO) { ch = 3; rg = r - NBZ;       yoff = WYO; psoff = WPSO; }
    else                    { ch = 1; rg = r - NBZ - NBO; yoff = WYG; psoff = WPSG; }
    int tot = RANGE * ch;
    for (int i = tid; i < tot; i += 256) s[i] = 0.0f;
    __syncthreads();
    unsigned c = cur[r];
    size_t b0 = (size_t)r * CAP;
    unsigned per = (c + SL - 1) / SL;
    unsigned s0 = sl * per, s1 = s0 + per; if (s1 > c) s1 = c;
    if (ch == 2) {
        const float2* y = (const float2*)(ws + yoff);
        for (unsigned j = s0 + tid; j < s1; j += 256) {
            uint2 q = rec[b0 + j];
            unsigned colr = q.x >> 17, row = q.x & 0x1FFFFu;
            float w = __uint_as_float(q.y);
            float2 yv = y[row];
            atomicAdd(&s[colr * 2],     w * yv.x);
            atomicAdd(&s[colr * 2 + 1], w * yv.y);
        }
    } else if (ch == 3) {
        const float4* y = (const float4*)(ws + yoff);
        for (unsigned j = s0 + tid; j < s1; j += 256) {
            uint2 q = rec[b0 + j];
            unsigned colr = q.x >> 17, row = q.x & 0x1FFFFu;
            float w = __uint_as_float(q.y);
            float4 yv = y[row];
            atomicAdd(&s[colr * 3],     w * yv.x);
            atomicAdd(&s[colr * 3 + 1], w * yv.y);
            atomicAdd(&s[colr * 3 + 2], w * yv.z);
        }
    } else {
        const float* y = ws + yoff;
        for (unsigned j = s0 + tid; j < s1; j += 256) {
            uint2 q = rec[b0 + j];
            atomicAdd(&s[q.x >> 17], __uint_as_float(q.y) * y[q.x & 0x1FFFFu]);
        }
    }
    __syncthreads();
    float* o = ws + psoff + (size_t)(rg * SL + sl) * tot;
    for (int i = tid * 4; i < tot; i += 1024)
        *(float4*)&o[i] = *(float4*)&s[i];
}

// K5: u = dinv * (y + sum_slices partial_s)
__global__ void k_u(float* __restrict__ ws) {
    int p = blockIdx.x * blockDim.x + threadIdx.x;
    if (p >= PAD_TOT) return;
    int r = p >> RSHIFT, i = p & (RANGE - 1);
    float di = ws[WDINV + p];
    if (p < OUT_PAD_BASE) {
        if (p >= N_ZONE) return;
        float s0 = ws[WYZ + 2 * p], s1 = ws[WYZ + 2 * p + 1];
#pragma unroll
        for (int sl = 0; sl < SL; sl++) {
            const float* ps = ws + WPSZ + (size_t)(r * SL + sl) * RANGE * 2;
            s0 += ps[2 * i]; s1 += ps[2 * i + 1];
        }
        ws[WUZ + 2 * p] = di * s0; ws[WUZ + 2 * p + 1] = di * s1;
    } else if (p < GND_PAD_BASE) {
        int idx = p - OUT_PAD_BASE;
        if (idx >= N_OUT) return;
        int rg = r - NBZ;
        float s0 = ws[WYO + 4 * idx], s1 = ws[WYO + 4 * idx + 1], s2 = ws[WYO + 4 * idx + 2];
#pragma unroll
        for (int sl = 0; sl < SL; sl++) {
            const float* ps = ws + WPSO + (size_t)(rg * SL + sl) * RANGE * 3;
            s0 += ps[3 * i]; s1 += ps[3 * i + 1]; s2 += ps[3 * i + 2];
        }
        ws[WUO + 4 * idx] = di * s0; ws[WUO + 4 * idx + 1] = di * s1; ws[WUO + 4 * idx + 2] = di * s2;
    } else {
        int idx = p - GND_PAD_BASE;
        if (idx >= N_GND) return;
        int rg = r - NBZ - NBO;
        float s0 = ws[WYG + idx];
#pragma unroll
        for (int sl = 0; sl < SL; sl++)
            s0 += ws[WPSG + (size_t)(rg * SL + sl) * RANGE + i];
        ws[WUG + idx] = di * s0;
    }
}

// K6: out = relu(u @ W + b), float4 stores
__global__ void k_fin2(const float* __restrict__ ws,
                       const float* __restrict__ Wz, const float* __restrict__ bz,
                       const float* __restrict__ Wo, const float* __restrict__ bo,
                       const float* __restrict__ Wg, const float* __restrict__ bg,
                       float* __restrict__ out) {
    int t = blockIdx.x * blockDim.x + threadIdx.x;
    const int TZ4 = N_ZONE * 16, TO4 = TZ4 + N_OUT * 16, TG4 = TO4 + N_GND * 16;
    if (t < TZ4) {
        int i = t >> 4, jb = (t & 15) << 2;
        float u0 = ws[WUZ + 2 * i], u1 = ws[WUZ + 2 * i + 1];
        float4 w0 = *(const float4*)(Wz + jb);
        float4 w1 = *(const float4*)(Wz + HID + jb);
        float4 bv = *(const float4*)(bz + jb);
        float4 o;
        o.x = fmaxf(bv.x + u0 * w0.x + u1 * w1.x, 0.0f);
        o.y = fmaxf(bv.y + u0 * w0.y + u1 * w1.y, 0.0f);
        o.z = fmaxf(bv.z + u0 * w0.z + u1 * w1.z, 0.0f);
        o.w = fmaxf(bv.w + u0 * w0.w + u1 * w1.w, 0.0f);
        *(float4*)(out + i * HID + jb) = o;
    } else if (t < TO4) {
        int q = t - TZ4;
        int i = q >> 4, jb = (q & 15) << 2;
        const float* u = ws + WUO + 4 * i;
        float u0 = u[0], u1 = u[1], u2 = u[2];
        float4 w0 = *(const float4*)(Wo + jb);
        float4 w1 = *(const float4*)(Wo + HID + jb);
        float4 w2 = *(const float4*)(Wo + 2 * HID + jb);
        float4 bv = *(const float4*)(bo + jb);
        float4 o;
        o.x = fmaxf(bv.x + u0 * w0.x + u1 * w1.x + u2 * w2.x, 0.0f);
        o.y = fmaxf(bv.y + u0 * w0.y + u1 * w1.y + u2 * w2.y, 0.0f);
        o.z = fmaxf(bv.z + u0 * w0.z + u1 * w1.z + u2 * w2.z, 0.0f);
        o.w = fmaxf(bv.w + u0 * w0.w + u1 * w1.w + u2 * w2.w, 0.0f);
        *(float4*)(out + N_ZONE * HID + i * HID + jb) = o;
    } else if (t < TG4) {
        int q = t - TO4;
        int i = q >> 4, jb = (q & 15) << 2;
        float u0 = ws[WUG + i];
        float4 w0 = *(const float4*)(Wg + jb);
        float4 bv = *(const float4*)(bg + jb);
        float4 o;
        o.x = fmaxf(bv.x + u0 * w0.x, 0.0f);
        o.y = fmaxf(bv.y + u0 * w0.y, 0.0f);
        o.z = fmaxf(bv.z + u0 * w0.z, 0.0f);
        o.w = fmaxf(bv.w + u0 * w0.w, 0.0f);
        *(float4*)(out + (N_ZONE + N_OUT) * HID + i * HID + jb) = o;
    }
}

// ---------------- fallback path (proven R1 kernels, 2.4 MB ws) ----------------
#define F_DEG_Z   0
#define F_DEG_O   (N_ZONE)
#define F_DEG_G   (N_ZONE + N_OUT)
#define F_DEG_TOT N_TOT
#define F_S_Z     F_DEG_TOT
#define F_S_O     (F_S_Z + N_ZONE * 2)
#define F_S_G     (F_S_O + N_OUT * 3)
#define F_TOT     (F_S_G + N_GND * 1)

__global__ void f_init(float* __restrict__ ws) {
    int i = blockIdx.x * blockDim.x + threadIdx.x;
    if (i < F_TOT) ws[i] = (i < F_DEG_TOT) ? 1.0f : 0.0f;
}
__global__ void f_deg(const int* __restrict__ eiz, const float* __restrict__ wz,
                      const int* __restrict__ eio, const float* __restrict__ wo,
                      const int* __restrict__ eig, const float* __restrict__ wg,
                      float* __restrict__ ws) {
    int t = blockIdx.x * blockDim.x + threadIdx.x;
    if (t < E_ZONE) atomicAdd(ws + F_DEG_Z + eiz[E_ZONE + t], wz[t]);
    else if (t < E_ZONE + E_OUT) { int e = t - E_ZONE; atomicAdd(ws + F_DEG_O + eio[E_OUT + e], wo[e]); }
    else if (t < E_ZONE + E_OUT + E_GND) { int e = t - E_ZONE - E_OUT; atomicAdd(ws + F_DEG_G + eig[E_GND + e], wg[e]); }
}
__global__ void f_dinv(float* __restrict__ ws) {
    int i = blockIdx.x * blockDim.x + threadIdx.x;
    if (i < F_DEG_TOT) ws[i] = 1.0f / sqrtf(ws[i]);
}
__global__ void f_scatter(const int* __restrict__ eiz, const float* __restrict__ wz, const float* __restrict__ xz,
                          const int* __restrict__ eio, const float* __restrict__ wo, const float* __restrict__ xo,
                          const int* __restrict__ eig, const float* __restrict__ wg, const float* __restrict__ xg,
                          float* __restrict__ ws) {
    int t = blockIdx.x * blockDim.x + threadIdx.x;
    if (t < E_ZONE) {
        int row = eiz[t], col = eiz[E_ZONE + t];
        float n = ws[F_DEG_Z + row] * wz[t] * ws[F_DEG_Z + col];
        atomicAdd(ws + F_S_Z + col * 2 + 0, n * xz[row * 2 + 0]);
        atomicAdd(ws + F_S_Z + col * 2 + 1, n * xz[row * 2 + 1]);
    } else if (t < E_ZONE + E_OUT) {
        int e = t - E_ZONE;
        int row = eio[e], col = eio[E_OUT + e];
        float n = ws[F_DEG_O + row] * wo[e] * ws[F_DEG_O + col];
        atomicAdd(ws + F_S_O + col * 3 + 0, n * xo[row * 3 + 0]);
        atomicAdd(ws + F_S_O + col * 3 + 1, n * xo[row * 3 + 1]);
        atomicAdd(ws + F_S_O + col * 3 + 2, n * xo[row * 3 + 2]);
    } else if (t < E_ZONE + E_OUT + E_GND) {
        int e = t - E_ZONE - E_OUT;
        int row = eig[e], col = eig[E_GND + e];
        float n = ws[F_DEG_G + row] * wg[e] * ws[F_DEG_G + col];
        atomicAdd(ws + F_S_G + col, n * xg[row]);
    }
}
__global__ void f_final(const float* __restrict__ ws,
                        const float* __restrict__ xz, const float* __restrict__ Wz, const float* __restrict__ bz,
                        const float* __restrict__ xo, const float* __restrict__ Wo, const float* __restrict__ bo,
                        const float* __restrict__ xg, const float* __restrict__ Wg, const float* __restrict__ bg,
                        float* __restrict__ out) {
    int t = blockIdx.x * blockDim.x + threadIdx.x;
    const int TZ = N_ZONE * HID, TO = TZ + N_OUT * HID, TG = TO + N_GND * HID;
    if (t < TZ) {
        int i = t >> 6, j = t & 63;
        float di = ws[F_DEG_Z + i], d2 = di * di;
        float t0 = ws[F_S_Z + i * 2 + 0] + d2 * xz[i * 2 + 0];
        float t1 = ws[F_S_Z + i * 2 + 1] + d2 * xz[i * 2 + 1];
        out[t] = fmaxf(bz[j] + t0 * Wz[j] + t1 * Wz[HID + j], 0.0f);
    } else if (t < TO) {
        int u = t - TZ;
        int i = u >> 6, j = u & 63;
        float di = ws[F_DEG_O + i], d2 = di * di;
        float t0 = ws[F_S_O + i * 3 + 0] + d2 * xo[i * 3 + 0];
        float t1 = ws[F_S_O + i * 3 + 1] + d2 * xo[i * 3 + 1];
        float t2 = ws[F_S_O + i * 3 + 2] + d2 * xo[i * 3 + 2];
        out[t] = fmaxf(bo[j] + t0 * Wo[j] + t1 * Wo[HID + j] + t2 * Wo[2 * HID + j], 0.0f);
    } else if (t < TG) {
        int u = t - TO;
        int i = u >> 6, j = u & 63;
        float di = ws[F_DEG_G + i], d2 = di * di;
        float t0 = ws[F_S_G + i] + d2 * xg[i];
        out[t] = fmaxf(bg[j] + t0 * Wg[j], 0.0f);
    }
}

extern "C" void kernel_launch(void* const* d_in, const int* in_sizes, int n_in,
                              void* d_out, int out_size, void* d_ws, size_t ws_size,
                              hipStream_t stream) {
    const float* xz = (const float*)d_in[0];
    const float* xo = (const float*)d_in[1];
    const float* xg = (const float*)d_in[2];
    const int*  eiz = (const int*)d_in[3];
    const int*  eio = (const int*)d_in[4];
    const int*  eig = (const int*)d_in[5];
    const float* Wz = (const float*)d_in[6];
    const float* Wo = (const float*)d_in[7];
    const float* Wg = (const float*)d_in[8];
    const float* bz = (const float*)d_in[9];
    const float* bo = (const float*)d_in[10];
    const float* bg = (const float*)d_in[11];
    const float* wz = (const float*)d_in[12];
    const float* wo = (const float*)d_in[13];
    const float* wg = (const float*)d_in[14];
    float* out = (float*)d_out;
    float* ws  = (float*)d_ws;

    const int B = 256;

    if (ws_size >= FAST_WS_BYTES) {
        unsigned* cur = (unsigned*)(ws + WCUR);
        uint2* rec = (uint2*)(ws + WREC);
        hipMemsetAsync(cur, 0, 128 * 4, stream);
        k_bin<<<NCHUNK, B, 0, stream>>>(eiz, wz, eio, wo, eig, wg, cur, rec);
        k_degp<<<NBUCKET * SL, B, 0, stream>>>(rec, cur, ws + WPDEG);
        k_dinvy<<<(PAD_TOT + B - 1) / B, B, 0, stream>>>(xz, xo, xg, ws);
        k_sp<<<NBUCKET * SL, B, 0, stream>>>(ws);
        k_u<<<(PAD_TOT + B - 1) / B, B, 0, stream>>>(ws);
        k_fin2<<<(N_TOT * HID / 4 + B - 1) / B, B, 0, stream>>>(ws, Wz, bz, Wo, bo, Wg, bg, out);
    } else {
        const int E_TOT = E_TOTAL, OUT_TOT = N_TOT * HID;
        f_init<<<(F_TOT + B - 1) / B, B, 0, stream>>>(ws);
        f_deg<<<(E_TOT + B - 1) / B, B, 0, stream>>>(eiz, wz, eio, wo, eig, wg, ws);
        f_dinv<<<(F_DEG_TOT + B - 1) / B, B, 0, stream>>>(ws);
        f_scatter<<<(E_TOT + B - 1) / B, B, 0, stream>>>(eiz, wz, xz, eio, wo, xo, eig, wg, xg, ws);
        f_final<<<(OUT_TOT + B - 1) / B, B, 0, stream>>>(ws, xz, Wz, bz, xo, Wo, bo, xg, Wg, bg, out);
    }
}